// Round 6
// baseline (854.861 us; speedup 1.0000x reference)
//
#include <hip/hip_runtime.h>
#include <cstdint>
#include <cstddef>

typedef unsigned short u16;
typedef short s8v __attribute__((ext_vector_type(8)));
typedef float f4v __attribute__((ext_vector_type(4)));

static __device__ __forceinline__ u16 f2bf(float x) {
  union { float f; uint32_t u; } v; v.f = x;
  uint32_t r = v.u + 0x7fffu + ((v.u >> 16) & 1u);   // RNE
  return (u16)(r >> 16);
}
static __device__ __forceinline__ uint2 f2bf4(float4 v) {
  uint2 r;
  r.x = (uint32_t)f2bf(v.x) | ((uint32_t)f2bf(v.y) << 16);
  r.y = (uint32_t)f2bf(v.z) | ((uint32_t)f2bf(v.w) << 16);
  return r;
}
static __device__ __forceinline__ float sigm(float x) { return 1.0f / (1.0f + __expf(-x)); }

// async global->LDS, 16B per lane; LDS dest = wave-uniform base + lane*16 (HW rule)
typedef __attribute__((address_space(3))) uint32_t lds_u32;
typedef const __attribute__((address_space(1))) uint32_t glb_u32;
static __device__ __forceinline__ void gload16(const void* g, void* l) {
  __builtin_amdgcn_global_load_lds((glb_u32*)g, (lds_u32*)l, 16, 0, 0);
}

// ---------------- prep (vectorized float4): bf16 conversions + emb gather + bias + sync-zero --
__global__ void kPrep(const float* __restrict__ fcW, const float* __restrict__ attnW,
                      const float* __restrict__ Wih, const float* __restrict__ bih,
                      const float* __restrict__ bhh, const float* __restrict__ embW,
                      const int* __restrict__ decX,
                      u16* __restrict__ fcWb, u16* __restrict__ attnWb, u16* __restrict__ Wihb,
                      u16* __restrict__ embg, float* __restrict__ biassum,
                      int* __restrict__ syncp) {
  const long NF4 = 4096000L, NA4 = 131072L, NW4 = 131072L, NE4 = 131072L, NB = 2048L, NS = 1024L;
  const long total = NF4 + NA4 + NW4 + NE4 + NB + NS;
  for (long i = (long)blockIdx.x * blockDim.x + threadIdx.x; i < total;
       i += (long)gridDim.x * blockDim.x) {
    if (i < NF4) {
      ((uint2*)fcWb)[i] = f2bf4(((const float4*)fcW)[i]);
    } else if (i < NF4 + NA4) {
      long k = i - NF4;
      ((uint2*)attnWb)[k] = f2bf4(((const float4*)attnW)[k]);
    } else if (i < NF4 + NA4 + NW4) {
      long k = i - NF4 - NA4;
      ((uint2*)Wihb)[k] = f2bf4(((const float4*)Wih)[k]);
    } else if (i < NF4 + NA4 + NW4 + NE4) {
      long k = i - NF4 - NA4 - NW4;                  // float4 index into embg [2048][64]
      int row = (int)(k >> 6), e4 = (int)(k & 63);   // row = t*32+b
      int t = row >> 5, b = row & 31;
      int x = decX[b * 64 + t];
      float4 v = *(const float4*)&embW[(long)x * 256 + e4 * 4];  // emb_W[0] all-zero => pad ok
      ((uint2*)embg)[k] = f2bf4(v);
    } else if (i < NF4 + NA4 + NW4 + NE4 + NB) {
      long k = i - NF4 - NA4 - NW4 - NE4;
      biassum[k] = bih[k] + bhh[k];
    } else {
      long k = i - NF4 - NA4 - NW4 - NE4 - NB;
      syncp[k] = 0;                                  // barrier/enroll counters (ws is poisoned)
    }
  }
}

// ---------------- templated bf16 MFMA GEMM: C[M,N] = A[M,K] * B[N,K]^T + bias ----------------
// BM=BN=128, BK=32, 4 waves. Staging via global_load_lds (width 16): LDS stays linear in
// lane order; the frag-major permutation is applied to the per-lane GLOBAL address instead
// (slot s -> m=(s>>6)*16+(s&15), q=(s>>4)&3; within a wave: m=d*16+(lane&15), q=lane>>4).
// SWZ: bijective XCD swizzle (requires gridDim.x*gridDim.y % 8 == 0) for B-panel L2 reuse.
template <int ACT, int OUTBF, int SWZ>
__global__ __launch_bounds__(256) void kGemm(const u16* __restrict__ A, const u16* __restrict__ Bm,
                                             const float* __restrict__ bias,
                                             float* __restrict__ Cf, u16* __restrict__ Cb,
                                             int N, int K) {
  __shared__ u16 lA[8 * 64 * 8];
  __shared__ u16 lB[8 * 64 * 8];
  const int tid = threadIdx.x;
  int bxx = blockIdx.x, byy = blockIdx.y;
  if (SWZ) {
    int id = byy * gridDim.x + bxx;
    int cpx = (gridDim.x * gridDim.y) >> 3;          // blocks per XCD
    int l = (id & 7) * cpx + (id >> 3);
    bxx = l % gridDim.x; byy = l / gridDim.x;
  }
  const int m0 = bxx * 128, n0 = byy * 128;
  const int lane = tid & 63, wid = tid >> 6;
  const int wm = wid >> 1, wn = wid & 1;
  f4v acc[4][4] = {};
  const int nkt = K >> 5;
  for (int kt = 0; kt < nkt; ++kt) {
    const int k0 = kt << 5;
#pragma unroll
    for (int i = 0; i < 2; ++i) {
      const int d = i * 4 + wid;
      const int m = (d << 4) | (lane & 15);
      const int q = lane >> 4;
      gload16(A + (size_t)(m0 + m) * K + k0 + q * 8, &lA[(i * 256 + wid * 64) * 8]);
      gload16(Bm + (size_t)(n0 + m) * K + k0 + q * 8, &lB[(i * 256 + wid * 64) * 8]);
    }
    __syncthreads();   // compiler emits s_waitcnt vmcnt(0) before the barrier
    s8v af[4], bfr[4];
#pragma unroll
    for (int i = 0; i < 4; ++i) af[i] = *(const s8v*)&lA[((wm * 4 + i) * 64 + lane) * 8];
#pragma unroll
    for (int j = 0; j < 4; ++j) bfr[j] = *(const s8v*)&lB[((wn * 4 + j) * 64 + lane) * 8];
#pragma unroll
    for (int i = 0; i < 4; ++i)
#pragma unroll
      for (int j = 0; j < 4; ++j)
        acc[i][j] = __builtin_amdgcn_mfma_f32_16x16x32_bf16(af[i], bfr[j], acc[i][j], 0, 0, 0);
    __syncthreads();
  }
  const int rq = lane >> 4, cl = lane & 15;
#pragma unroll
  for (int j = 0; j < 4; ++j) {
    int col = n0 + wn * 64 + j * 16 + cl;
    float bv = bias[col];
#pragma unroll
    for (int i = 0; i < 4; ++i) {
      int rowb = m0 + wm * 64 + i * 16 + rq * 4;
      f4v v = acc[i][j];
#pragma unroll
      for (int r = 0; r < 4; ++r) {
        float x = v[r] + bv;
        if (ACT) x = tanhf(x);
        size_t off = (size_t)(rowb + r) * N + col;
        if (OUTBF) Cb[off] = f2bf(x); else Cf[off] = x;
      }
    }
  }
}

// ---------------- XCD-local persistent LSTM, Whh in registers, L2-LOCAL barrier ----------------
// (unchanged from R5: 240 us, matched prediction)
__global__ __launch_bounds__(256, 1) void kLSTM4(const float* __restrict__ Gpre,
                                                 const float* __restrict__ Whh,
                                                 const float* __restrict__ h0,
                                                 const float* __restrict__ c0,
                                                 float* __restrict__ Hall,
                                                 float* __restrict__ hx,
                                                 float* __restrict__ cx,
                                                 int* __restrict__ syncp) {
  __shared__ float4 hl4[5160];       // 82,560 B: h stage uses [0..511]; size forces 1 blk/CU
  __shared__ int srank;
  const int tid = threadIdx.x;

  int xcc;
  asm volatile("s_getreg_b32 %0, hwreg(HW_REG_XCC_ID)" : "=s"(xcc));
  xcc &= 7;
  if (tid == 0) srank = atomicAdd(&syncp[xcc * 64], 1);   // enroll (device scope, once)
  __syncthreads();
  const int rank = srank & 31;
  const int j0 = rank * 16;          // 16 h-columns owned by this block
  const int b0 = xcc * 4;            // 4 batches owned by this XCD
  int* cnt = &syncp[(8 + xcc) * 64]; // per-XCD barrier counter (own 256B line)

  const int jj = tid >> 4;           // 0..15: column within block
  const int ks = tid & 15;           // K-slice during compute; (g,bb) after the fold
  const int g_o = ks >> 2, bb_o = ks & 3;
  const int b_o = b0 + bb_o;
  const int j_o = j0 + jj;
  const bool cellLane = (g_o == 0);

  // Whh slice -> registers, once. W[g][i] = Whh[g*512 + j0 + jj][(ks+16i)*4 .. +3]
  const float4* W4 = (const float4*)Whh;   // row stride 128 float4
  float4 Wr[4][8];
#pragma unroll
  for (int g = 0; g < 4; ++g) {
    const int row = g * 512 + j0 + jj;
#pragma unroll
    for (int i = 0; i < 8; ++i) Wr[g][i] = W4[(size_t)row * 128 + ks + 16 * i];
  }

  float creg = cellLane ? c0[b_o * 512 + j_o] : 0.f;
  const float4* hsrc = (const float4*)h0;
  float gpv = Gpre[(size_t)b_o * 2048 + (size_t)g_o * 512 + j_o];   // t=0 gate-pre

  for (int t = 0; t < 64; ++t) {
    // stage h_{t-1} for our 4 batches (8KB) into LDS
#pragma unroll
    for (int it = 0; it < 2; ++it) {
      int idx = it * 256 + tid;      // 0..511 float4 chunks
      int hb = idx >> 7, k4 = idx & 127;
      hl4[idx] = hsrc[(b0 + hb) * 128 + k4];
    }
    __syncthreads();

    // prefetch next step's gate-pre (consumed after the next barrier -> latency hidden)
    float gnext = 0.f;
    if (t < 63)
      gnext = Gpre[((size_t)(t + 1) * 32 + b_o) * 2048 + (size_t)g_o * 512 + j_o];

    // 512 FMA into 16 partials; h via 32 broadcast ds_read_b128
    float acc[16];
#pragma unroll
    for (int p = 0; p < 16; ++p) acc[p] = 0.f;
#pragma unroll
    for (int i = 0; i < 8; ++i) {
      float4 h4[4];
#pragma unroll
      for (int bb = 0; bb < 4; ++bb) h4[bb] = hl4[bb * 128 + ks + 16 * i];
#pragma unroll
      for (int g = 0; g < 4; ++g) {
        float4 w = Wr[g][i];
#pragma unroll
        for (int bb = 0; bb < 4; ++bb)
          acc[g * 4 + bb] += w.x * h4[bb].x + w.y * h4[bb].y + w.z * h4[bb].z + w.w * h4[bb].w;
      }
    }

    // fold-reduce 16 partials across the 16 ks-lanes: lane ks ends with total for p=ks
#define FOLD_STAGE(OFF, NN)                                        \
    {                                                              \
      const bool hi = (ks & OFF) != 0;                             \
      _Pragma("unroll")                                            \
      for (int q = 0; q < NN; ++q) {                               \
        float keepv = hi ? acc[q + NN] : acc[q];                   \
        float sendv = hi ? acc[q] : acc[q + NN];                   \
        acc[q] = keepv + __shfl_xor(sendv, OFF, 64);               \
      }                                                            \
    }
    FOLD_STAGE(8, 8)
    FOLD_STAGE(4, 4)
    FOLD_STAGE(2, 2)
    FOLD_STAGE(1, 1)
#undef FOLD_STAGE

    float pre = acc[0] + gpv;
    // activations: one per lane (g lives in lane bits 2..3), gather f,g,o into i-lanes
    float v = (g_o == 2) ? tanhf(pre) : sigm(pre);
    float fv = __shfl_xor(v, 4, 64);
    float gv = __shfl_xor(v, 8, 64);
    float ov = __shfl_xor(v, 12, 64);
    float* hdst = Hall + (size_t)t * 16384;
    if (cellLane) {
      creg = fv * creg + v * gv;               // v = i-gate
      float hv = ov * tanhf(creg);
      hdst[b_o * 512 + j_o] = hv;
      if (t == 63) { hx[b_o * 512 + j_o] = hv; cx[b_o * 512 + j_o] = creg; }
    }
    __syncthreads();                 // compiler emits vmcnt(0): all waves' h stores are in L2

    if (t < 63) {
      if (tid == 0) {
        // arrive: L2-local atomic (no sc1 => executes at this XCD's L2)
        unsigned one = 1u;
        asm volatile("global_atomic_add %0, %1, off"
                     :: "v"(cnt), "v"(one) : "memory");
        const int target = 32 * (t + 1);
        unsigned zero = 0u, old;
        for (;;) {
          // poll: atomic-add-0 with sc0 (returns pre-value; L2-resident, never stale L1)
          asm volatile("global_atomic_add %0, %1, %2, off sc0\n\t"
                       "s_waitcnt vmcnt(0)"
                       : "=v"(old) : "v"(cnt), "v"(zero) : "memory");
          if ((int)old >= target) break;
          __builtin_amdgcn_s_sleep(1);
        }
      }
      __syncthreads();               // whole block held until XCD barrier passes
    }
    gpv = gnext;
    hsrc = (const float4*)hdst;
  }
}

// ---------------- attention: scores -> softmax -> context; emit CAT=[h|c_t] in bf16 ----------
__global__ __launch_bounds__(256) void kAttn(const float* __restrict__ Hall, const float* __restrict__ enc,
                                             u16* __restrict__ CAT) {
  const int bx = blockIdx.x;
  const int b = bx >> 3, tg = bx & 7;     // 8 timesteps per block
  const int tid = threadIdx.x;
  __shared__ float sh[8][516];
  __shared__ float sa[8][132];
  __shared__ float red[8][32];
  for (int tt = 0; tt < 8; ++tt) {
    int t = tg * 8 + tt;
    const float* hr = Hall + ((size_t)t * 32 + b) * 512;
    u16* cr = CAT + ((size_t)(b * 64 + t)) * 1024;
    for (int k = tid; k < 512; k += 256) { float v = hr[k]; sh[tt][k] = v; cr[k] = f2bf(v); }
  }
  __syncthreads();
  {  // scores: thread = (t_local = tid&7, e_base = tid>>3)
    const int tl = tid & 7, eb = tid >> 3;
#pragma unroll
    for (int u = 0; u < 4; ++u) {
      int e = eb + u * 32;
      const float* er = enc + ((size_t)b * 128 + e) * 512;
      float a = 0.f;
      for (int k = 0; k < 512; k += 4) {
        float4 ev = *(const float4*)&er[k];
        float4 hv = *(const float4*)&sh[tl][k];
        a += ev.x * hv.x + ev.y * hv.y + ev.z * hv.z + ev.w * hv.w;
      }
      sa[tl][e] = a;
    }
  }
  __syncthreads();
  {  // softmax over 128 per t
    const int g = tid >> 5, l = tid & 31;
    float mx = -1e30f;
#pragma unroll
    for (int u = 0; u < 4; ++u) mx = fmaxf(mx, sa[g][l + u * 32]);
    red[g][l] = mx;
    __syncthreads();
    if (l == 0) {
      float m2 = -1e30f;
      for (int i = 0; i < 32; ++i) m2 = fmaxf(m2, red[g][i]);
      sa[g][128] = m2;
    }
    __syncthreads();
    float m2 = sa[g][128];
    float s = 0.f;
#pragma unroll
    for (int u = 0; u < 4; ++u) { int e = l + u * 32; float p = __expf(sa[g][e] - m2); sa[g][e] = p; s += p; }
    red[g][l] = s;
    __syncthreads();
    if (l == 0) {
      float s2 = 0.f;
      for (int i = 0; i < 32; ++i) s2 += red[g][i];
      sa[g][129] = 1.0f / s2;
    }
    __syncthreads();
    float inv = sa[g][129];
#pragma unroll
    for (int u = 0; u < 4; ++u) sa[g][l + u * 32] *= inv;
  }
  __syncthreads();
  {  // context: thread covers cols 2*tid, 2*tid+1 for all 8 t
    float a0[8], a1[8];
#pragma unroll
    for (int tt = 0; tt < 8; ++tt) { a0[tt] = 0.f; a1[tt] = 0.f; }
    const float* eb2 = enc + (size_t)b * 128 * 512 + tid * 2;
    for (int e = 0; e < 128; ++e) {
      float2 v = *(const float2*)&eb2[(size_t)e * 512];
#pragma unroll
      for (int tt = 0; tt < 8; ++tt) { float a = sa[tt][e]; a0[tt] += a * v.x; a1[tt] += a * v.y; }
    }
#pragma unroll
    for (int tt = 0; tt < 8; ++tt) {
      int t = tg * 8 + tt;
      u16* cr = CAT + ((size_t)(b * 64 + t)) * 1024 + 512;
      cr[tid * 2] = f2bf(a0[tt]); cr[tid * 2 + 1] = f2bf(a1[tt]);
    }
  }
}

// ---------------- launcher ----------------
extern "C" void kernel_launch(void* const* d_in, const int* in_sizes, int n_in,
                              void* d_out, int out_size, void* d_ws, size_t ws_size,
                              hipStream_t stream) {
  const int*   decX  = (const int*)d_in[0];
  const float* enc   = (const float*)d_in[1];
  const float* h0    = (const float*)d_in[2];
  const float* c0    = (const float*)d_in[3];
  const float* embW  = (const float*)d_in[4];
  const float* Wih   = (const float*)d_in[5];
  const float* Whh   = (const float*)d_in[6];
  const float* bih   = (const float*)d_in[7];
  const float* bhh   = (const float*)d_in[8];
  const float* attnW = (const float*)d_in[9];
  const float* attnb = (const float*)d_in[10];
  const float* fcW   = (const float*)d_in[11];
  const float* fcb   = (const float*)d_in[12];
  float* out = (float*)d_out;

  char* ws = (char*)d_ws;
  u16*   fcWb    = (u16*)(ws);                    // 32,768,000 B
  u16*   attnWb  = (u16*)(ws + 32768000);         //  1,048,576 B
  u16*   Wihb    = (u16*)(ws + 33816576);         //  1,048,576 B
  u16*   embg    = (u16*)(ws + 34865152);         //  1,048,576 B
  float* biassum = (float*)(ws + 35913728);       //      8,192 B
  float* Gpre    = (float*)(ws + 35921920);       // 16,777,216 B
  float* Hall    = (float*)(ws + 52699136);       //  4,194,304 B
  u16*   CAT     = (u16*)(ws + 56893440);         //  4,194,304 B
  u16*   OUTb    = (u16*)(ws + 61087744);         //  2,097,152 B
  int*   syncp   = (int*)(ws + 63184896);         //      4,096 B  (total ~63.2 MB)

  hipLaunchKernelGGL(kPrep, dim3(4096), dim3(256), 0, stream,
                     fcW, attnW, Wih, bih, bhh, embW, decX, fcWb, attnWb, Wihb, embg, biassum,
                     syncp);
  // G_pre[t*32+b][2048] = embg @ Wih^T + (b_ih+b_hh)
  hipLaunchKernelGGL((kGemm<0, 0, 0>), dim3(16, 16), dim3(256), 0, stream,
                     embg, Wihb, biassum, Gpre, (u16*)nullptr, 2048, 256);
  // LSTM recurrence: one cooperative kernel, XCD-local batch partition, L2-local barriers.
  {
    float* hx = out + 65536000L;             // final h
    float* cx = out + 65536000L + 16384L;    // final c
    const float* gpreA = Gpre; const float* whhA = Whh;
    const float* h0A = h0;     const float* c0A = c0;
    float* hallA = Hall;       int* syncA = syncp;
    void* args[] = {(void*)&gpreA, (void*)&whhA, (void*)&h0A, (void*)&c0A,
                    (void*)&hallA, (void*)&hx, (void*)&cx, (void*)&syncA};
    hipLaunchCooperativeKernel((void*)kLSTM4, dim3(256), dim3(256), args, 0, stream);
  }
  hipLaunchKernelGGL(kAttn, dim3(256), dim3(256), 0, stream, Hall, enc, CAT);
  // OUT[m][512] = tanh(CAT @ attnW^T + attn_b), bf16
  hipLaunchKernelGGL((kGemm<1, 1, 0>), dim3(16, 4), dim3(256), 0, stream,
                     CAT, attnWb, attnb, (float*)nullptr, OUTb, 512, 1024);
  // logits[m][32000] = OUT @ fcW^T + fc_b  (m = b*64+t => contiguous [B,T,V] output)
  // SWZ=1: 4000 blocks % 8 == 0 -> bijective; same-B-panel blocks land on one XCD.
  hipLaunchKernelGGL((kGemm<0, 0, 1>), dim3(16, 250), dim3(256), 0, stream,
                     OUTb, fcWb, fcb, out, (u16*)nullptr, 32000, 512);
}